// Round 2
// baseline (224.955 us; speedup 1.0000x reference)
//
#include <hip/hip_runtime.h>
#include <math.h>

#define T_STEPS 32
#define B_EV    256
#define N_HITS  500000
#define N_PFO   4096
#define NQ      (N_HITS / 4)   // 125000 float4 column-quads
#define QPB     64             // quads per block in k_assign

// Workspace layout (bytes):
//   [0,64)      double sums[8]: 0=dir 1=mag 2=pid 3=chg 4=stop 5=assign
//   [64,80)     int icnt[4]:    0=valid_pfo_count 1=assign_valid_count
//   [80,1104)   int ppe[256]
//   [1104,2128) int first_idx[256]

__device__ __forceinline__ float softplusf(float x) {
    // log(1+exp(x)), numerically stable
    return fmaxf(x, 0.f) + __logf(1.f + __expf(-fabsf(x)));
}

__device__ __forceinline__ float waveReduceF(float v) {
#pragma unroll
    for (int o = 32; o > 0; o >>= 1) v += __shfl_down(v, o, 64);
    return v;
}
__device__ __forceinline__ int waveReduceI(int v) {
#pragma unroll
    for (int o = 32; o > 0; o >>= 1) v += __shfl_down(v, o, 64);
    return v;
}

__device__ __forceinline__ int lowerBound(const int* __restrict__ a, int n, int key) {
    int lo = 0, hi = n;
    while (lo < hi) {
        int m = (lo + hi) >> 1;
        if (a[m] < key) lo = m + 1; else hi = m;
    }
    return lo;
}

// --- Kernel 1: ppe / first_idx via binary search over sorted gt_batch; zero accumulators.
__global__ void k_setup(const int* __restrict__ gt_batch,
                        double* __restrict__ sums, int* __restrict__ icnt,
                        int* __restrict__ ppe, int* __restrict__ first_idx) {
    int b = threadIdx.x;  // one block of 256
    if (b < 8) sums[b] = 0.0;
    if (b >= 8 && b < 12) icnt[b - 8] = 0;
    int lb = lowerBound(gt_batch, N_PFO, b);
    int ub = lowerBound(gt_batch, N_PFO, b + 1);
    ppe[b] = ub - lb;
    first_idx[b] = lb;
}

// --- Kernel 2: per-pfo losses (dir/mag/pid/charge) + stop BCE, fused.
__global__ void k_small(const float* __restrict__ pfo_mom, const float* __restrict__ pfo_pmod,
                        const float* __restrict__ pfo_pid, const float* __restrict__ pfo_chg,
                        const float* __restrict__ stop_logits,
                        const float* __restrict__ gt_mom, const float* __restrict__ gt_pmod,
                        const float* __restrict__ gt_pid, const float* __restrict__ gt_chg,
                        const int* __restrict__ gt_batch,
                        const int* __restrict__ ppe, const int* __restrict__ first_idx,
                        double* __restrict__ sums, int* __restrict__ icnt) {
    int tid = blockIdx.x * blockDim.x + threadIdx.x;
    float s_stop = 0.f, s_dir = 0.f, s_mag = 0.f, s_pid = 0.f, s_chg = 0.f;
    int cnt = 0;

    if (tid < T_STEPS * B_EV) {  // stop loss over (T,B)
        int t = tid >> 8, b = tid & 255;
        float x = stop_logits[tid];
        float z = (t >= ppe[b]) ? 1.f : 0.f;
        s_stop = softplusf(x) - x * z;
    }

    if (tid < N_PFO) {
        int i = tid;
        int b = gt_batch[i];
        int step = i - first_idx[b];
        if (step < T_STEPS) {
            cnt = 1;
            int base = step * B_EV + b;
            // direction: 1 - cosine similarity (normalize with eps=1e-8)
            float p0 = pfo_mom[base * 3 + 0], p1 = pfo_mom[base * 3 + 1], p2 = pfo_mom[base * 3 + 2];
            float g0 = gt_mom[i * 3 + 0],    g1 = gt_mom[i * 3 + 1],    g2 = gt_mom[i * 3 + 2];
            float pn = fmaxf(sqrtf(p0 * p0 + p1 * p1 + p2 * p2), 1e-8f);
            float gn = fmaxf(sqrtf(g0 * g0 + g1 * g1 + g2 * g2), 1e-8f);
            float cs = (p0 * g0 + p1 * g1 + p2 * g2) / (pn * gn);
            s_dir = 1.f - cs;
            // magnitude MSE
            float dm = pfo_pmod[base] - gt_pmod[i];
            s_mag = dm * dm;
            // PID: NLL vs argmax(gt_pid) (first-max tie-break like jnp.argmax)
            int cls = 0;
            float best = gt_pid[i * 5];
#pragma unroll
            for (int c = 1; c < 5; c++) {
                float v = gt_pid[i * 5 + c];
                if (v > best) { best = v; cls = c; }
            }
            float l[5];
#pragma unroll
            for (int c = 0; c < 5; c++) l[c] = pfo_pid[base * 5 + c];
            float m = l[0];
#pragma unroll
            for (int c = 1; c < 5; c++) m = fmaxf(m, l[c]);
            float se = 0.f;
#pragma unroll
            for (int c = 0; c < 5; c++) se += __expf(l[c] - m);
            float lse = __logf(se) + m;
            s_pid = lse - l[cls];
            // charge MSE
            float dc = pfo_chg[base] - gt_chg[i];
            s_chg = dc * dc;
        }
    }

    s_dir = waveReduceF(s_dir);
    s_mag = waveReduceF(s_mag);
    s_pid = waveReduceF(s_pid);
    s_chg = waveReduceF(s_chg);
    s_stop = waveReduceF(s_stop);
    cnt = waveReduceI(cnt);
    if ((threadIdx.x & 63) == 0) {
        atomicAdd(&sums[0], (double)s_dir);
        atomicAdd(&sums[1], (double)s_mag);
        atomicAdd(&sums[2], (double)s_pid);
        atomicAdd(&sums[3], (double)s_chg);
        atomicAdd(&sums[4], (double)s_stop);
        atomicAdd(&icnt[0], cnt);
    }
}

// --- Kernel 3: assignment BCE over (T,N). 2D work split: block = 64 quads x 32 rows,
// thread (tt = tid>>6 in [0,4), qq = tid&63) handles rows t = tt, tt+4, ... for quad qq.
// Per-quad validity v (=min(ppe[hit_batch],T)) and hit_to_pfo packed into LDS bytes.
__global__ void __launch_bounds__(256) k_assign(const float* __restrict__ A,
                                                const int* __restrict__ hit_to_pfo,
                                                const int* __restrict__ hit_batch,
                                                const int* __restrict__ ppe,
                                                double* __restrict__ sums, int* __restrict__ icnt) {
    __shared__ int s_ppe[B_EV];
    __shared__ int s_v[QPB];    // 4 x 8-bit per-column valid counts
    __shared__ int s_hp[QPB];   // 4 x 8-bit hit_to_pfo

    int tid = threadIdx.x;
    int q0 = blockIdx.x * QPB;

    s_ppe[tid] = min(ppe[tid], T_STEPS);
    __syncthreads();

    int cnt = 0;
    if (tid < QPB) {
        int q = q0 + tid;
        int vp = 0, hpp = 0;
        if (q < NQ) {
            int4 hb = *(const int4*)(hit_batch + q * 4);
            int4 hp = *(const int4*)(hit_to_pfo + q * 4);
            int v0 = s_ppe[hb.x], v1 = s_ppe[hb.y], v2 = s_ppe[hb.z], v3 = s_ppe[hb.w];
            vp = v0 | (v1 << 8) | (v2 << 16) | (v3 << 24);
            hpp = hp.x | (hp.y << 8) | (hp.z << 16) | (hp.w << 24);
            cnt = v0 + v1 + v2 + v3;   // counted once per quad (only tt==0 threads)
        }
        s_v[tid] = vp;
        s_hp[tid] = hpp;
    }
    __syncthreads();

    int qq = tid & 63;
    int tt = tid >> 6;            // 0..3
    int vp = s_v[qq];
    int hpp = s_hp[qq];
    int v0 = vp & 255, v1 = (vp >> 8) & 255, v2 = (vp >> 16) & 255, v3 = (vp >> 24) & 255;
    int h0 = hpp & 255, h1 = (hpp >> 8) & 255, h2 = (hpp >> 16) & 255, h3 = (hpp >> 24) & 255;
    int vmax = max(max(v0, v1), max(v2, v3));

    float s = 0.f;
    const float* col = A + (size_t)(q0 + qq) * 4;
    for (int t = tt; t < vmax; t += 4) {
        float4 x = *(const float4*)(col + (size_t)t * N_HITS);
        if (t < v0) s += softplusf(x.x) - ((t == h0) ? x.x : 0.f);
        if (t < v1) s += softplusf(x.y) - ((t == h1) ? x.y : 0.f);
        if (t < v2) s += softplusf(x.z) - ((t == h2) ? x.z : 0.f);
        if (t < v3) s += softplusf(x.w) - ((t == h3) ? x.w : 0.f);
    }

    s = waveReduceF(s);
    cnt = waveReduceI(cnt);
    if ((tid & 63) == 0) {
        atomicAdd(&sums[5], (double)s);
        atomicAdd(&icnt[1], cnt);
    }
}

// --- Kernel 4: finalize the 7 outputs.
__global__ void k_final(const double* __restrict__ sums, const int* __restrict__ icnt,
                        float* __restrict__ out) {
    if (threadIdx.x == 0 && blockIdx.x == 0) {
        double vc = (double)(icnt[0] > 1 ? icnt[0] : 1);
        double ac = (double)(icnt[1] > 1 ? icnt[1] : 1);
        double dir = sums[0] / vc;
        double mag = sums[1] / vc;
        double pid = sums[2] / vc;
        double chg = sums[3] / vc;
        double stp = sums[4] / (double)(T_STEPS * B_EV);
        double asn = sums[5] / ac;
        double total = 1.0 * dir + 1.0 * mag + 1.0 * pid + 0.5 * chg + 1.0 * asn + 0.5 * stp;
        out[0] = (float)total;
        out[1] = (float)dir;
        out[2] = (float)mag;
        out[3] = (float)pid;
        out[4] = (float)chg;
        out[5] = (float)asn;
        out[6] = (float)stp;
    }
}

extern "C" void kernel_launch(void* const* d_in, const int* in_sizes, int n_in,
                              void* d_out, int out_size, void* d_ws, size_t ws_size,
                              hipStream_t stream) {
    (void)in_sizes; (void)n_in; (void)out_size; (void)ws_size;
    const float* pfo_mom   = (const float*)d_in[0];
    const float* pfo_pmod  = (const float*)d_in[1];
    const float* pfo_pid   = (const float*)d_in[2];
    const float* pfo_chg   = (const float*)d_in[3];
    const float* assign_lg = (const float*)d_in[4];
    const float* stop_lg   = (const float*)d_in[5];
    const float* gt_mom    = (const float*)d_in[6];
    const float* gt_pmod   = (const float*)d_in[7];
    const float* gt_pid    = (const float*)d_in[8];
    const float* gt_chg    = (const float*)d_in[9];
    const int*   gt_batch  = (const int*)d_in[10];
    const int*   hit_to_pfo= (const int*)d_in[11];
    const int*   hit_batch = (const int*)d_in[12];
    float* out = (float*)d_out;

    char* ws = (char*)d_ws;
    double* sums    = (double*)(ws + 0);
    int*    icnt    = (int*)(ws + 64);
    int*    ppe     = (int*)(ws + 80);
    int*    firstIx = (int*)(ws + 1104);

    k_setup<<<1, 256, 0, stream>>>(gt_batch, sums, icnt, ppe, firstIx);
    k_small<<<(T_STEPS * B_EV) / 256, 256, 0, stream>>>(
        pfo_mom, pfo_pmod, pfo_pid, pfo_chg, stop_lg,
        gt_mom, gt_pmod, gt_pid, gt_chg, gt_batch, ppe, firstIx, sums, icnt);
    int nblk = (NQ + QPB - 1) / QPB;
    k_assign<<<nblk, 256, 0, stream>>>(assign_lg, hit_to_pfo, hit_batch, ppe, sums, icnt);
    k_final<<<1, 64, 0, stream>>>(sums, icnt, out);
}

// Round 3
// 140.033 us; speedup vs baseline: 1.6064x; 1.6064x over previous
//
#include <hip/hip_runtime.h>
#include <math.h>

#define T_STEPS 32
#define B_EV    256
#define N_HITS  500000
#define N_PFO   4096
#define NQ      (N_HITS / 4)   // 125000 float4 column-quads
#define QPB     64             // quads per block in k_assign
#define NSLOT   32             // assign partial-sum slots (one 128B line each)

// Workspace layout (bytes):
//   [0,4096)      double psum[32*16]  assign partial sums, slot i at psum[i*16]
//   [4096,4160)   double sums[8]: 0=dir 1=mag 2=pid 3=chg 4=stop
//   [4160,4176)   int icnt[4]:    0=valid_pfo_count 1=assign_valid_count
//   [4176,5200)   int ppe[256]
//   [5200,6224)   int first_idx[256]

__device__ __forceinline__ float softplusf(float x) {
    return fmaxf(x, 0.f) + __logf(1.f + __expf(-fabsf(x)));
}

__device__ __forceinline__ float waveReduceF(float v) {
#pragma unroll
    for (int o = 32; o > 0; o >>= 1) v += __shfl_down(v, o, 64);
    return v;
}
__device__ __forceinline__ long waveReduceL(long v) {
#pragma unroll
    for (int o = 32; o > 0; o >>= 1) v += __shfl_down(v, o, 64);
    return v;
}

__device__ __forceinline__ int lowerBound(const int* __restrict__ a, int n, int key) {
    int lo = 0, hi = n;
    while (lo < hi) {
        int m = (lo + hi) >> 1;
        if (a[m] < key) lo = m + 1; else hi = m;
    }
    return lo;
}

// --- Kernel 1: ppe/first_idx via binary search over sorted gt_batch; counts computed
// analytically from sorted hit_batch (NO atomics needed later); zero accumulators.
__global__ void k_setup(const int* __restrict__ gt_batch, const int* __restrict__ hit_batch,
                        double* __restrict__ psum, double* __restrict__ sums,
                        int* __restrict__ icnt,
                        int* __restrict__ ppe, int* __restrict__ first_idx) {
    __shared__ long s_red[2][4];
    int b = threadIdx.x;  // one block of 256
    psum[b] = 0.0;
    psum[b + 256] = 0.0;
    if (b < 8) sums[b] = 0.0;

    int lb = lowerBound(gt_batch, N_PFO, b);
    int ub = lowerBound(gt_batch, N_PFO, b + 1);
    ppe[b] = ub - lb;
    first_idx[b] = lb;
    int vp = min(ub - lb, T_STEPS);

    int hlb = lowerBound(hit_batch, N_HITS, b);
    int hub = lowerBound(hit_batch, N_HITS, b + 1);
    long hc = (long)(hub - hlb) * vp;

    long v = waveReduceL((long)vp);
    long h = waveReduceL(hc);
    int w = b >> 6;
    if ((b & 63) == 0) { s_red[0][w] = v; s_red[1][w] = h; }
    __syncthreads();
    if (b == 0) {
        long tv = 0, th = 0;
#pragma unroll
        for (int i = 0; i < 4; i++) { tv += s_red[0][i]; th += s_red[1][i]; }
        icnt[0] = (int)tv;
        icnt[1] = (int)th;
    }
}

// --- Kernel 2: per-pfo losses (dir/mag/pid/charge) + stop BCE, fused. Block-level
// LDS reduction -> 6 atomics per block (32 blocks).
__global__ void k_small(const float* __restrict__ pfo_mom, const float* __restrict__ pfo_pmod,
                        const float* __restrict__ pfo_pid, const float* __restrict__ pfo_chg,
                        const float* __restrict__ stop_logits,
                        const float* __restrict__ gt_mom, const float* __restrict__ gt_pmod,
                        const float* __restrict__ gt_pid, const float* __restrict__ gt_chg,
                        const int* __restrict__ gt_batch,
                        const int* __restrict__ ppe, const int* __restrict__ first_idx,
                        double* __restrict__ sums) {
    __shared__ float s_red[5][4];
    int tid = blockIdx.x * blockDim.x + threadIdx.x;
    float s_stop = 0.f, s_dir = 0.f, s_mag = 0.f, s_pid = 0.f, s_chg = 0.f;

    if (tid < T_STEPS * B_EV) {  // stop loss over (T,B)
        int t = tid >> 8, b = tid & 255;
        float x = stop_logits[tid];
        float z = (t >= ppe[b]) ? 1.f : 0.f;
        s_stop = softplusf(x) - x * z;
    }

    if (tid < N_PFO) {
        int i = tid;
        int b = gt_batch[i];
        int step = i - first_idx[b];
        if (step < T_STEPS) {
            int base = step * B_EV + b;
            float p0 = pfo_mom[base * 3 + 0], p1 = pfo_mom[base * 3 + 1], p2 = pfo_mom[base * 3 + 2];
            float g0 = gt_mom[i * 3 + 0],    g1 = gt_mom[i * 3 + 1],    g2 = gt_mom[i * 3 + 2];
            float pn = fmaxf(sqrtf(p0 * p0 + p1 * p1 + p2 * p2), 1e-8f);
            float gn = fmaxf(sqrtf(g0 * g0 + g1 * g1 + g2 * g2), 1e-8f);
            float cs = (p0 * g0 + p1 * g1 + p2 * g2) / (pn * gn);
            s_dir = 1.f - cs;
            float dm = pfo_pmod[base] - gt_pmod[i];
            s_mag = dm * dm;
            int cls = 0;
            float best = gt_pid[i * 5];
#pragma unroll
            for (int c = 1; c < 5; c++) {
                float v = gt_pid[i * 5 + c];
                if (v > best) { best = v; cls = c; }
            }
            float l[5];
#pragma unroll
            for (int c = 0; c < 5; c++) l[c] = pfo_pid[base * 5 + c];
            float m = l[0];
#pragma unroll
            for (int c = 1; c < 5; c++) m = fmaxf(m, l[c]);
            float se = 0.f;
#pragma unroll
            for (int c = 0; c < 5; c++) se += __expf(l[c] - m);
            s_pid = __logf(se) + m - l[cls];
            float dc = pfo_chg[base] - gt_chg[i];
            s_chg = dc * dc;
        }
    }

    s_dir = waveReduceF(s_dir);
    s_mag = waveReduceF(s_mag);
    s_pid = waveReduceF(s_pid);
    s_chg = waveReduceF(s_chg);
    s_stop = waveReduceF(s_stop);
    int w = threadIdx.x >> 6;
    if ((threadIdx.x & 63) == 0) {
        s_red[0][w] = s_dir; s_red[1][w] = s_mag; s_red[2][w] = s_pid;
        s_red[3][w] = s_chg; s_red[4][w] = s_stop;
    }
    __syncthreads();
    if (threadIdx.x < 5) {
        float t = 0.f;
#pragma unroll
        for (int i = 0; i < 4; i++) t += s_red[threadIdx.x][i];
        atomicAdd(&sums[threadIdx.x], (double)t);
    }
}

// --- Kernel 3: assignment BCE over (T,N). Block = 64 quads x 32 rows; thread
// (tt = tid>>6, qq = tid&63) handles rows t = tt, tt+4, ... for quad qq.
// Block-level LDS reduction -> ONE double atomic per block, scattered over 32
// cache-line-padded slots.
__global__ void __launch_bounds__(256) k_assign(const float* __restrict__ A,
                                                const int* __restrict__ hit_to_pfo,
                                                const int* __restrict__ hit_batch,
                                                const int* __restrict__ ppe,
                                                double* __restrict__ psum) {
    __shared__ int s_ppe[B_EV];
    __shared__ int s_v[QPB];    // 4 x 8-bit per-column valid counts
    __shared__ int s_hp[QPB];   // 4 x 8-bit hit_to_pfo
    __shared__ float s_red[4];

    int tid = threadIdx.x;
    int q0 = blockIdx.x * QPB;

    s_ppe[tid] = min(ppe[tid], T_STEPS);
    __syncthreads();

    if (tid < QPB) {
        int q = q0 + tid;
        int vp = 0, hpp = 0;
        if (q < NQ) {
            int4 hb = *(const int4*)(hit_batch + q * 4);
            int4 hp = *(const int4*)(hit_to_pfo + q * 4);
            vp = s_ppe[hb.x] | (s_ppe[hb.y] << 8) | (s_ppe[hb.z] << 16) | (s_ppe[hb.w] << 24);
            hpp = hp.x | (hp.y << 8) | (hp.z << 16) | (hp.w << 24);
        }
        s_v[tid] = vp;
        s_hp[tid] = hpp;
    }
    __syncthreads();

    int qq = tid & 63;
    int tt = tid >> 6;            // 0..3
    int vp = s_v[qq];
    int hpp = s_hp[qq];
    int v0 = vp & 255, v1 = (vp >> 8) & 255, v2 = (vp >> 16) & 255, v3 = (vp >> 24) & 255;
    int h0 = hpp & 255, h1 = (hpp >> 8) & 255, h2 = (hpp >> 16) & 255, h3 = (hpp >> 24) & 255;
    int vmax = max(max(v0, v1), max(v2, v3));

    float s = 0.f;
    const float* col = A + (size_t)(q0 + qq) * 4;
    for (int t = tt; t < vmax; t += 4) {
        float4 x = *(const float4*)(col + (size_t)t * N_HITS);
        if (t < v0) s += softplusf(x.x) - ((t == h0) ? x.x : 0.f);
        if (t < v1) s += softplusf(x.y) - ((t == h1) ? x.y : 0.f);
        if (t < v2) s += softplusf(x.z) - ((t == h2) ? x.z : 0.f);
        if (t < v3) s += softplusf(x.w) - ((t == h3) ? x.w : 0.f);
    }

    s = waveReduceF(s);
    if ((tid & 63) == 0) s_red[tid >> 6] = s;
    __syncthreads();
    if (tid == 0) {
        float t = s_red[0] + s_red[1] + s_red[2] + s_red[3];
        atomicAdd(&psum[(blockIdx.x & (NSLOT - 1)) * 16], (double)t);
    }
}

// --- Kernel 4: finalize the 7 outputs.
__global__ void k_final(const double* __restrict__ psum, const double* __restrict__ sums,
                        const int* __restrict__ icnt, float* __restrict__ out) {
    if (threadIdx.x == 0 && blockIdx.x == 0) {
        double asum = 0.0;
#pragma unroll
        for (int i = 0; i < NSLOT; i++) asum += psum[i * 16];
        double vc = (double)(icnt[0] > 1 ? icnt[0] : 1);
        double ac = (double)(icnt[1] > 1 ? icnt[1] : 1);
        double dir = sums[0] / vc;
        double mag = sums[1] / vc;
        double pid = sums[2] / vc;
        double chg = sums[3] / vc;
        double stp = sums[4] / (double)(T_STEPS * B_EV);
        double asn = asum / ac;
        double total = 1.0 * dir + 1.0 * mag + 1.0 * pid + 0.5 * chg + 1.0 * asn + 0.5 * stp;
        out[0] = (float)total;
        out[1] = (float)dir;
        out[2] = (float)mag;
        out[3] = (float)pid;
        out[4] = (float)chg;
        out[5] = (float)asn;
        out[6] = (float)stp;
    }
}

extern "C" void kernel_launch(void* const* d_in, const int* in_sizes, int n_in,
                              void* d_out, int out_size, void* d_ws, size_t ws_size,
                              hipStream_t stream) {
    (void)in_sizes; (void)n_in; (void)out_size; (void)ws_size;
    const float* pfo_mom   = (const float*)d_in[0];
    const float* pfo_pmod  = (const float*)d_in[1];
    const float* pfo_pid   = (const float*)d_in[2];
    const float* pfo_chg   = (const float*)d_in[3];
    const float* assign_lg = (const float*)d_in[4];
    const float* stop_lg   = (const float*)d_in[5];
    const float* gt_mom    = (const float*)d_in[6];
    const float* gt_pmod   = (const float*)d_in[7];
    const float* gt_pid    = (const float*)d_in[8];
    const float* gt_chg    = (const float*)d_in[9];
    const int*   gt_batch  = (const int*)d_in[10];
    const int*   hit_to_pfo= (const int*)d_in[11];
    const int*   hit_batch = (const int*)d_in[12];
    float* out = (float*)d_out;

    char* ws = (char*)d_ws;
    double* psum    = (double*)(ws + 0);
    double* sums    = (double*)(ws + 4096);
    int*    icnt    = (int*)(ws + 4160);
    int*    ppe     = (int*)(ws + 4176);
    int*    firstIx = (int*)(ws + 5200);

    k_setup<<<1, 256, 0, stream>>>(gt_batch, hit_batch, psum, sums, icnt, ppe, firstIx);
    k_small<<<(T_STEPS * B_EV) / 256, 256, 0, stream>>>(
        pfo_mom, pfo_pmod, pfo_pid, pfo_chg, stop_lg,
        gt_mom, gt_pmod, gt_pid, gt_chg, gt_batch, ppe, firstIx, sums);
    int nblk = (NQ + QPB - 1) / QPB;
    k_assign<<<nblk, 256, 0, stream>>>(assign_lg, hit_to_pfo, hit_batch, ppe, psum);
    k_final<<<1, 64, 0, stream>>>(psum, sums, icnt, out);
}

// Round 4
// 132.253 us; speedup vs baseline: 1.7009x; 1.0588x over previous
//
#include <hip/hip_runtime.h>
#include <math.h>

#define T_STEPS 32
#define B_EV    256
#define N_HITS  500000
#define N_PFO   4096
#define NQ      (N_HITS / 4)          // 125000 float4 column-quads
#define QPB     64                    // quads per block
#define NBLK    ((NQ + QPB - 1) / QPB)  // 1954 blocks

// Workspace layout (bytes) — everything written unconditionally, no zero-init needed:
//   [0, NBLK*8)          float2 psumB[NBLK]   (assign partial sum, assign valid cnt)
//   [NBLK*8, +640)       float  psumA[5*32]   (dir/mag/pid/chg/stop per small-block)
//   [NBLK*8+640, +4)     int    icnt0         (valid pfo count)
#define WS_PSUMA (NBLK * 8)
#define WS_ICNT0 (NBLK * 8 + 640)

__device__ __forceinline__ float softplusf(float x) {
    return fmaxf(x, 0.f) + __logf(1.f + __expf(-fabsf(x)));
}

__device__ __forceinline__ float waveReduceF(float v) {
#pragma unroll
    for (int o = 32; o > 0; o >>= 1) v += __shfl_down(v, o, 64);
    return v;
}
__device__ __forceinline__ int waveReduceI(int v) {
#pragma unroll
    for (int o = 32; o > 0; o >>= 1) v += __shfl_down(v, o, 64);
    return v;
}
__device__ __forceinline__ double waveReduceD(double v) {
#pragma unroll
    for (int o = 32; o > 0; o >>= 1) v += __shfl_down(v, o, 64);
    return v;
}

__device__ __forceinline__ int lowerBound(const int* __restrict__ a, int n, int key) {
    int lo = 0, hi = n;
    while (lo < hi) {
        int m = (lo + hi) >> 1;
        if (a[m] < key) lo = m + 1; else hi = m;
    }
    return lo;
}

// --- Kernel 1: everything except the final reduction. 1954 blocks x 256.
// All blocks: assignment BCE for 64 column-quads (64 quads x 32 rows; thread
//   (tt=tid>>6, qq=tid&63) does rows t = tt, tt+4, ...). Per-quad validity from
//   memoized binary search over sorted gt_batch (hit_batch sorted -> ~2 searches).
// Blocks 0..31: also stop BCE (t=blk, b=tid) and (blocks 0..15) per-pfo losses,
//   using an LDS run-start table s_lb[257] built from one search per thread.
// Block 0: also stores icnt0 = sum_b min(ppe[b],T).
__global__ void __launch_bounds__(256) k_main(
        const float* __restrict__ A,
        const int* __restrict__ hit_to_pfo, const int* __restrict__ hit_batch,
        const int* __restrict__ gt_batch,
        const float* __restrict__ pfo_mom, const float* __restrict__ pfo_pmod,
        const float* __restrict__ pfo_pid, const float* __restrict__ pfo_chg,
        const float* __restrict__ stop_logits,
        const float* __restrict__ gt_mom, const float* __restrict__ gt_pmod,
        const float* __restrict__ gt_pid, const float* __restrict__ gt_chg,
        float2* __restrict__ psumB, float* __restrict__ psumA,
        int* __restrict__ icnt0) {
    __shared__ int   s_lb[257];
    __shared__ int   s_v[QPB];
    __shared__ int   s_hp[QPB];
    __shared__ float s_redS[4];
    __shared__ float s_red5[5][4];
    __shared__ int   s_redI[4];
    __shared__ int   s_cnt;

    int tid = threadIdx.x, blk = blockIdx.x;
    bool small = (blk < 32);

    // --- phase 1a: per-quad validity + targets (wave 0 only)
    int mycnt = 0;
    if (tid < QPB) {
        int q = blk * QPB + tid;
        int myv = 0, myhp = 0;
        if (q < NQ) {
            int4 hb = *(const int4*)(hit_batch + q * 4);
            int4 hp = *(const int4*)(hit_to_pfo + q * 4);
            int bs[4] = {hb.x, hb.y, hb.z, hb.w};
            int v[4];
            int lastb = -1, lb = 0, ub = 0;
#pragma unroll
            for (int k = 0; k < 4; k++) {
                int b = bs[k];
                if (b != lastb) {
                    lb = lowerBound(gt_batch, N_PFO, b);
                    ub = lowerBound(gt_batch, N_PFO, b + 1);
                    lastb = b;
                }
                v[k] = min(ub - lb, T_STEPS);
            }
            myv = v[0] | (v[1] << 8) | (v[2] << 16) | (v[3] << 24);
            myhp = hp.x | (hp.y << 8) | (hp.z << 16) | (hp.w << 24);
            mycnt = v[0] + v[1] + v[2] + v[3];
        }
        s_v[tid] = myv;
        s_hp[tid] = myhp;
    }

    // --- phase 1b: run-start table for small blocks
    if (small) {
        s_lb[tid] = lowerBound(gt_batch, N_PFO, tid);
        if (tid == 0) s_lb[256] = N_PFO;
    }
    __syncthreads();

    // --- phase 2a: small losses (blocks 0..31)
    float s_stop = 0.f, s_dir = 0.f, s_mag = 0.f, s_pid = 0.f, s_chg = 0.f;
    if (small) {
        int ppe_b = s_lb[tid + 1] - s_lb[tid];
        float x = stop_logits[blk * B_EV + tid];       // t=blk, b=tid
        float z = (blk >= ppe_b) ? 1.f : 0.f;
        s_stop = softplusf(x) - x * z;

        if (blk == 0) {                                // icnt0 partials
            int vpb = waveReduceI(min(ppe_b, T_STEPS));
            if ((tid & 63) == 0) s_redI[tid >> 6] = vpb;
        }

        if (blk < 16) {                                // per-pfo losses, i in [0,4096)
            int i = blk * B_EV + tid;
            int b = gt_batch[i];
            int step = i - s_lb[b];
            if (step < T_STEPS) {
                int base = step * B_EV + b;
                float p0 = pfo_mom[base * 3 + 0], p1 = pfo_mom[base * 3 + 1], p2 = pfo_mom[base * 3 + 2];
                float g0 = gt_mom[i * 3 + 0],    g1 = gt_mom[i * 3 + 1],    g2 = gt_mom[i * 3 + 2];
                float pn = fmaxf(sqrtf(p0 * p0 + p1 * p1 + p2 * p2), 1e-8f);
                float gn = fmaxf(sqrtf(g0 * g0 + g1 * g1 + g2 * g2), 1e-8f);
                float cs = (p0 * g0 + p1 * g1 + p2 * g2) / (pn * gn);
                s_dir = 1.f - cs;
                float dm = pfo_pmod[base] - gt_pmod[i];
                s_mag = dm * dm;
                int cls = 0;
                float best = gt_pid[i * 5];
#pragma unroll
                for (int c = 1; c < 5; c++) {
                    float v = gt_pid[i * 5 + c];
                    if (v > best) { best = v; cls = c; }
                }
                float l[5];
#pragma unroll
                for (int c = 0; c < 5; c++) l[c] = pfo_pid[base * 5 + c];
                float m = l[0];
#pragma unroll
                for (int c = 1; c < 5; c++) m = fmaxf(m, l[c]);
                float se = 0.f;
#pragma unroll
                for (int c = 0; c < 5; c++) se += __expf(l[c] - m);
                s_pid = __logf(se) + m - l[cls];
                float dc = pfo_chg[base] - gt_chg[i];
                s_chg = dc * dc;
            }
        }
    }

    // --- phase 2b: assignment BCE loop (all blocks)
    int qq = tid & 63;
    int tt = tid >> 6;                                 // 0..3
    int vp = s_v[qq];
    int hpp = s_hp[qq];
    int v0 = vp & 255, v1 = (vp >> 8) & 255, v2 = (vp >> 16) & 255, v3 = (vp >> 24) & 255;
    int h0 = hpp & 255, h1 = (hpp >> 8) & 255, h2 = (hpp >> 16) & 255, h3 = (hpp >> 24) & 255;
    int vmax = max(max(v0, v1), max(v2, v3));

    float s = 0.f;
    const float* col = A + ((size_t)blk * QPB + qq) * 4;
    for (int t = tt; t < vmax; t += 4) {
        float4 x = *(const float4*)(col + (size_t)t * N_HITS);
        if (t < v0) s += softplusf(x.x) - ((t == h0) ? x.x : 0.f);
        if (t < v1) s += softplusf(x.y) - ((t == h1) ? x.y : 0.f);
        if (t < v2) s += softplusf(x.z) - ((t == h2) ? x.z : 0.f);
        if (t < v3) s += softplusf(x.w) - ((t == h3) ? x.w : 0.f);
    }

    // --- phase 3: reductions + plain stores (no atomics)
    s = waveReduceF(s);
    if ((tid & 63) == 0) s_redS[tid >> 6] = s;
    int cnt = waveReduceI(mycnt);                      // quads live in wave 0 only
    if (tid == 0) s_cnt = cnt;
    int w = tid >> 6;
    if (small) {
        s_dir = waveReduceF(s_dir);
        s_mag = waveReduceF(s_mag);
        s_pid = waveReduceF(s_pid);
        s_chg = waveReduceF(s_chg);
        s_stop = waveReduceF(s_stop);
        if ((tid & 63) == 0) {
            s_red5[0][w] = s_dir; s_red5[1][w] = s_mag; s_red5[2][w] = s_pid;
            s_red5[3][w] = s_chg; s_red5[4][w] = s_stop;
        }
    }
    __syncthreads();
    if (tid == 0) {
        float tot = s_redS[0] + s_redS[1] + s_redS[2] + s_redS[3];
        psumB[blk] = make_float2(tot, (float)s_cnt);
    }
    if (small && tid < 5) {
        float t = 0.f;
#pragma unroll
        for (int i = 0; i < 4; i++) t += s_red5[tid][i];
        psumA[tid * 32 + blk] = t;
    }
    if (blk == 0 && tid == 1) {
        *icnt0 = s_redI[0] + s_redI[1] + s_redI[2] + s_redI[3];
    }
}

// --- Kernel 2: reduce partials, write the 7 outputs.
__global__ void k_final(const float2* __restrict__ psumB, const float* __restrict__ psumA,
                        const int* __restrict__ icnt0, float* __restrict__ out) {
    __shared__ double s_rd[4], s_rc[4];
    int tid = threadIdx.x;  // one block of 256
    double s = 0.0, c = 0.0;
    for (int i = tid; i < NBLK; i += 256) {
        float2 v = psumB[i];
        s += (double)v.x;
        c += (double)v.y;
    }
    s = waveReduceD(s);
    c = waveReduceD(c);
    if ((tid & 63) == 0) { s_rd[tid >> 6] = s; s_rc[tid >> 6] = c; }
    __syncthreads();
    if (tid == 0) {
        double asum = s_rd[0] + s_rd[1] + s_rd[2] + s_rd[3];
        double acnt = s_rc[0] + s_rc[1] + s_rc[2] + s_rc[3];
        double sm[5];
#pragma unroll
        for (int cc = 0; cc < 5; cc++) {
            double t = 0.0;
            for (int i = 0; i < 32; i++) t += (double)psumA[cc * 32 + i];
            sm[cc] = t;
        }
        double vc = (double)max(*icnt0, 1);
        double ac = (acnt > 1.0) ? acnt : 1.0;
        double dir = sm[0] / vc;
        double mag = sm[1] / vc;
        double pid = sm[2] / vc;
        double chg = sm[3] / vc;
        double stp = sm[4] / (double)(T_STEPS * B_EV);
        double asn = asum / ac;
        double total = dir + mag + pid + 0.5 * chg + asn + 0.5 * stp;
        out[0] = (float)total;
        out[1] = (float)dir;
        out[2] = (float)mag;
        out[3] = (float)pid;
        out[4] = (float)chg;
        out[5] = (float)asn;
        out[6] = (float)stp;
    }
}

extern "C" void kernel_launch(void* const* d_in, const int* in_sizes, int n_in,
                              void* d_out, int out_size, void* d_ws, size_t ws_size,
                              hipStream_t stream) {
    (void)in_sizes; (void)n_in; (void)out_size; (void)ws_size;
    const float* pfo_mom   = (const float*)d_in[0];
    const float* pfo_pmod  = (const float*)d_in[1];
    const float* pfo_pid   = (const float*)d_in[2];
    const float* pfo_chg   = (const float*)d_in[3];
    const float* assign_lg = (const float*)d_in[4];
    const float* stop_lg   = (const float*)d_in[5];
    const float* gt_mom    = (const float*)d_in[6];
    const float* gt_pmod   = (const float*)d_in[7];
    const float* gt_pid    = (const float*)d_in[8];
    const float* gt_chg    = (const float*)d_in[9];
    const int*   gt_batch  = (const int*)d_in[10];
    const int*   hit_to_pfo= (const int*)d_in[11];
    const int*   hit_batch = (const int*)d_in[12];
    float* out = (float*)d_out;

    char* ws = (char*)d_ws;
    float2* psumB = (float2*)(ws + 0);
    float*  psumA = (float*)(ws + WS_PSUMA);
    int*    icnt0 = (int*)(ws + WS_ICNT0);

    k_main<<<NBLK, 256, 0, stream>>>(assign_lg, hit_to_pfo, hit_batch, gt_batch,
                                     pfo_mom, pfo_pmod, pfo_pid, pfo_chg, stop_lg,
                                     gt_mom, gt_pmod, gt_pid, gt_chg,
                                     psumB, psumA, icnt0);
    k_final<<<1, 256, 0, stream>>>(psumB, psumA, icnt0, out);
}